// Round 6
// baseline (134.793 us; speedup 1.0000x reference)
//
#include <hip/hip_runtime.h>

typedef float f32x4 __attribute__((ext_vector_type(4)));
typedef __bf16 bf16x8 __attribute__((ext_vector_type(8)));
typedef __bf16 bf16x4 __attribute__((ext_vector_type(4)));

#define T_ 2048
#define DE 1024
#define DQ 64
#define SCALE 0.125f

#define GL16(gp, lp)                                                        \
  __builtin_amdgcn_global_load_lds(                                         \
      (const __attribute__((address_space(1))) void*)(gp),                  \
      (__attribute__((address_space(3))) void*)(lp), 16, 0, 0)

#define WAITVM(N) asm volatile("s_waitcnt vmcnt(" #N ")" ::: "memory")

// ---------- kernel 0: pack W (3x [1024][64] f32) into fragment-major bf16 Wf.
// Wf[(kc*12 + t)*64 + lane][8]: elem j = W[kc*32+(lane>>4)*8+j][(t&3)*16+(lane&15)],
// matrix = t>>2, kc = k/32.  (validated in R5)
__global__ __launch_bounds__(256) void kw_pack(
    const float* __restrict__ Wq, const float* __restrict__ Wk,
    const float* __restrict__ Wv, __bf16* __restrict__ Wf)
{
  int tid = blockIdx.x * 256 + threadIdx.x;   // 0..24575 = f*64 + lane
  int lane = tid & 63, f = tid >> 6;
  int t = f % 12, kc = f / 12;
  const float* W = (t < 4) ? Wq : ((t < 8) ? Wk : Wv);
  int nl = (t & 3) * 16 + (lane & 15);
  int k0 = kc * 32 + (lane >> 4) * 8;
  bf16x8 v;
#pragma unroll
  for (int j = 0; j < 8; ++j) v[j] = (__bf16)W[(size_t)(k0 + j) * 64 + nl];
  *(bf16x8*)(Wf + (size_t)tid * 8) = v;
}

// ---------- kernel 1: QKV projection. Block = 64 m-rows, 4 waves (one 16-row m-sub
// each, all 12 n-tiles). x staged via global_load_lds: 3 buffers, counted vmcnt(4),
// one raw s_barrier per k-step (no drain). W frags reg-direct from L2.
__global__ __launch_bounds__(256) void kproj(
    const float* __restrict__ x, const __bf16* __restrict__ Wf,
    __bf16* __restrict__ Qb, __bf16* __restrict__ Kb, __bf16* __restrict__ Vt)
{
  __shared__ float xs[3][64 * 64];            // 3 x 16 KB
  const int tid = threadIdx.x;
  const int lane = tid & 63;
  const int w = tid >> 6;
  const int col = lane & 15, g = lane >> 4;
  const int mbase = blockIdx.x * 64;

  // staging map: 4 chunks of 16B per thread per k-step. slot = cc*256+tid,
  // row = slot>>4, 16B-slot c = slot&15. LDS dest linear; global src pre-swizzled
  // by s=(row&7)<<5 (same involution applied on the read side).
  size_t gsrc[4];
  int ldst[4];
#pragma unroll
  for (int cc = 0; cc < 4; ++cc) {
    int slot = cc * 256 + tid;
    int row = slot >> 4, c = slot & 15;
    int kbyte = (c * 16) ^ ((row & 7) << 5);
    gsrc[cc] = ((size_t)(mbase + row) << 12) + (size_t)kbyte;
    ldst[cc] = slot * 16;
  }

  f32x4 acc[12];
#pragma unroll
  for (int i = 0; i < 12; ++i) acc[i] = (f32x4){0.f, 0.f, 0.f, 0.f};

  const char* xb = (const char*)x;

#define STAGE(ks, bi)                                                       \
  {                                                                         \
    char* lb = (char*)&xs[bi][0];                                           \
    _Pragma("unroll")                                                       \
    for (int cc = 0; cc < 4; ++cc)                                          \
      GL16(xb + gsrc[cc] + (size_t)(ks) * 256, lb + ldst[cc]);              \
  }

  // compute one k-step (64 k) from buffer bi
#define KSTEP(ks, bi)                                                       \
  {                                                                         \
    const char* base = (const char*)&xs[bi][0] + (w * 16 + col) * 256;      \
    const int sw = (col & 7) << 5;                                          \
    _Pragma("unroll")                                                       \
    for (int kh = 0; kh < 2; ++kh) {                                        \
      f32x4 a0 = *(const f32x4*)(base + ((kh * 128 + g * 32) ^ sw));        \
      f32x4 a1 = *(const f32x4*)(base + (((kh * 128 + g * 32) + 16) ^ sw)); \
      bf16x8 af;                                                            \
      _Pragma("unroll")                                                     \
      for (int j = 0; j < 4; ++j) { af[j] = (__bf16)a0[j]; af[4 + j] = (__bf16)a1[j]; } \
      const __bf16* Wp = Wf + ((size_t)(((ks) * 2 + kh) * 12) * 64 + lane) * 8; \
      _Pragma("unroll")                                                     \
      for (int nt = 0; nt < 12; ++nt) {                                     \
        bf16x8 bfr = *(const bf16x8*)(Wp + (size_t)nt * 512);               \
        acc[nt] = __builtin_amdgcn_mfma_f32_16x16x32_bf16(af, bfr, acc[nt], 0, 0, 0); \
      }                                                                     \
    }                                                                       \
  }

  STAGE(0, 0);
  for (int ks = 0; ks < 15; ++ks) {
    STAGE(ks + 1, (ks + 1) % 3);
    WAITVM(4);                                // own prev-step stage landed
    __builtin_amdgcn_s_barrier();             // => all waves' stage for ks landed
    __builtin_amdgcn_sched_barrier(0);
    KSTEP(ks, ks % 3);
  }
  WAITVM(0);
  __builtin_amdgcn_s_barrier();
  __builtin_amdgcn_sched_barrier(0);
  KSTEP(15, 15 % 3);

#undef STAGE
#undef KSTEP

  // epilogue: D layout row = g*4+r (within 16-row m-sub), col = ti*16 + col
  const int b = mbase >> 11;
  const int mrow = mbase + w * 16 + g * 4;
  const int trow = (mbase & 2047) + w * 16 + g * 4;
#pragma unroll
  for (int ti = 0; ti < 12; ++ti) {
    if (ti < 8) {
      __bf16* dst = (ti < 4) ? Qb : Kb;
      int c = (ti & 3) * 16 + col;
#pragma unroll
      for (int r = 0; r < 4; ++r)
        dst[(size_t)(mrow + r) * DQ + c] = (__bf16)acc[ti][r];
    } else {
      int d = (ti - 8) * 16 + col;
      bf16x4 v;
#pragma unroll
      for (int r = 0; r < 4; ++r) v[r] = (__bf16)acc[ti][r];
      *(bf16x4*)(Vt + ((size_t)(b * DQ + d)) * T_ + trow) = v;
    }
  }
}

// ---------- kernel 2: causal flash attention (R3 version, proven ~22us).
// Block = 32 q-rows, 4 waves split KV (KVB=64), LDS combine.
__global__ __launch_bounds__(256) void kattn(
    const __bf16* __restrict__ Qb, const __bf16* __restrict__ Kb,
    const __bf16* __restrict__ Vt, float* __restrict__ out)
{
  __shared__ float accs[4][32][68];
  __shared__ float mls[4][2][32];
  __shared__ __bf16 plds[4][2][16][72];

  const int tid = threadIdx.x;
  const int lane = tid & 63;
  const int w = tid >> 6;
  const int col = lane & 15, g = lane >> 4;
  const int b = blockIdx.x & 7;
  const int jq = 63 - (blockIdx.x >> 3);
  const int qbase = jq * 32;

  bf16x8 qa[2][2];
#pragma unroll
  for (int mt = 0; mt < 2; ++mt) {
    const __bf16* Qp = Qb + (size_t)(b * T_ + qbase + mt * 16 + col) * DQ + g * 8;
    qa[mt][0] = *(const bf16x8*)(Qp);
    qa[mt][1] = *(const bf16x8*)(Qp + 32);
  }

  const __bf16* Kbb = Kb + (size_t)b * T_ * DQ;
  const __bf16* Vbb = Vt + (size_t)b * DQ * T_;

  f32x4 acc[2][4];
#pragma unroll
  for (int mt = 0; mt < 2; ++mt)
#pragma unroll
    for (int dt = 0; dt < 4; ++dt) acc[mt][dt] = (f32x4){0.f,0.f,0.f,0.f};
  float mrun[2][4], lsum[2][4];
#pragma unroll
  for (int mt = 0; mt < 2; ++mt)
#pragma unroll
    for (int r = 0; r < 4; ++r) { mrun[mt][r] = -1e30f; lsum[mt][r] = 0.f; }

  const int nb = (jq >> 1) + 1;
  for (int it = w; it < nb; it += 4) {
    const int nbase = it * 64;

    bf16x8 kf_[4][2];
#pragma unroll
    for (int nt = 0; nt < 4; ++nt) {
      const __bf16* Kp = Kbb + (size_t)(nbase + nt * 16 + col) * DQ + g * 8;
      kf_[nt][0] = *(const bf16x8*)(Kp);
      kf_[nt][1] = *(const bf16x8*)(Kp + 32);
    }

    f32x4 s[2][4];
#pragma unroll
    for (int mt = 0; mt < 2; ++mt)
#pragma unroll
      for (int nt = 0; nt < 4; ++nt) {
        f32x4 t = __builtin_amdgcn_mfma_f32_16x16x32_bf16(qa[mt][0], kf_[nt][0],
                                                          (f32x4){0.f,0.f,0.f,0.f}, 0, 0, 0);
        s[mt][nt] = __builtin_amdgcn_mfma_f32_16x16x32_bf16(qa[mt][1], kf_[nt][1], t, 0, 0, 0);
      }

    bf16x8 vf[4][2];
#pragma unroll
    for (int dt = 0; dt < 4; ++dt) {
      const __bf16* Vp = Vbb + (size_t)(dt * 16 + col) * T_ + nbase + g * 8;
      vf[dt][0] = *(const bf16x8*)(Vp);
      vf[dt][1] = *(const bf16x8*)(Vp + 32);
    }

#pragma unroll
    for (int mt = 0; mt < 2; ++mt)
#pragma unroll
      for (int nt = 0; nt < 4; ++nt)
#pragma unroll
        for (int r = 0; r < 4; ++r) s[mt][nt][r] *= SCALE;
    if (it == nb - 1) {
#pragma unroll
      for (int mt = 0; mt < 2; ++mt)
#pragma unroll
        for (int nt = 0; nt < 4; ++nt)
#pragma unroll
          for (int r = 0; r < 4; ++r)
            if (nbase + nt * 16 + col > qbase + mt * 16 + g * 4 + r) s[mt][nt][r] = -1e30f;
    }

    float mv[2][4];
#pragma unroll
    for (int mt = 0; mt < 2; ++mt)
#pragma unroll
      for (int r = 0; r < 4; ++r)
        mv[mt][r] = fmaxf(fmaxf(s[mt][0][r], s[mt][1][r]), fmaxf(s[mt][2][r], s[mt][3][r]));
#pragma unroll
    for (int sh = 1; sh <= 8; sh <<= 1)
#pragma unroll
      for (int mt = 0; mt < 2; ++mt)
#pragma unroll
        for (int r = 0; r < 4; ++r) mv[mt][r] = fmaxf(mv[mt][r], __shfl_xor(mv[mt][r], sh, 64));

#pragma unroll
    for (int mt = 0; mt < 2; ++mt)
#pragma unroll
      for (int r = 0; r < 4; ++r) {
        float mn = fmaxf(mrun[mt][r], mv[mt][r]);
        float rs = __expf(mrun[mt][r] - mn);
        mrun[mt][r] = mn;
        float ps = 0.f;
#pragma unroll
        for (int nt = 0; nt < 4; ++nt) {
          s[mt][nt][r] = __expf(s[mt][nt][r] - mn);
          ps += s[mt][nt][r];
        }
        lsum[mt][r] = lsum[mt][r] * rs + ps;
#pragma unroll
        for (int dt = 0; dt < 4; ++dt) acc[mt][dt][r] *= rs;
      }

#pragma unroll
    for (int mt = 0; mt < 2; ++mt)
#pragma unroll
      for (int nt = 0; nt < 4; ++nt)
#pragma unroll
        for (int r = 0; r < 4; ++r)
          plds[w][mt][g * 4 + r][nt * 16 + col] = (__bf16)s[mt][nt][r];

    bf16x8 pa[2][2];
#pragma unroll
    for (int mt = 0; mt < 2; ++mt) {
      pa[mt][0] = *(const bf16x8*)&plds[w][mt][col][g * 8];
      pa[mt][1] = *(const bf16x8*)&plds[w][mt][col][32 + g * 8];
    }

#pragma unroll
    for (int mt = 0; mt < 2; ++mt)
#pragma unroll
      for (int dt = 0; dt < 4; ++dt) {
        f32x4 t = __builtin_amdgcn_mfma_f32_16x16x32_bf16(pa[mt][0], vf[dt][0], acc[mt][dt], 0, 0, 0);
        acc[mt][dt] = __builtin_amdgcn_mfma_f32_16x16x32_bf16(pa[mt][1], vf[dt][1], t, 0, 0, 0);
      }
  }

#pragma unroll
  for (int sh = 1; sh <= 8; sh <<= 1)
#pragma unroll
    for (int mt = 0; mt < 2; ++mt)
#pragma unroll
      for (int r = 0; r < 4; ++r) lsum[mt][r] += __shfl_xor(lsum[mt][r], sh, 64);

#pragma unroll
  for (int mt = 0; mt < 2; ++mt)
#pragma unroll
    for (int r = 0; r < 4; ++r) {
      int row = mt * 16 + g * 4 + r;
      accs[w][row][col]      = acc[mt][0][r];
      accs[w][row][col + 16] = acc[mt][1][r];
      accs[w][row][col + 32] = acc[mt][2][r];
      accs[w][row][col + 48] = acc[mt][3][r];
      if (col == 0) { mls[w][0][row] = mrun[mt][r]; mls[w][1][row] = lsum[mt][r]; }
    }
  __syncthreads();

#pragma unroll
  for (int pass = 0; pass < 2; ++pass) {
    int row = pass * 16 + (tid >> 4);
    int c4 = (tid & 15) * 4;
    float m0 = mls[0][0][row], m1 = mls[1][0][row];
    float m2 = mls[2][0][row], m3 = mls[3][0][row];
    float M = fmaxf(fmaxf(m0, m1), fmaxf(m2, m3));
    float s0 = __expf(m0 - M), s1 = __expf(m1 - M);
    float s2 = __expf(m2 - M), s3 = __expf(m3 - M);
    float L = s0 * mls[0][1][row] + s1 * mls[1][1][row]
            + s2 * mls[2][1][row] + s3 * mls[3][1][row];
    f32x4 a0 = *(const f32x4*)&accs[0][row][c4];
    f32x4 a1 = *(const f32x4*)&accs[1][row][c4];
    f32x4 a2 = *(const f32x4*)&accs[2][row][c4];
    f32x4 a3 = *(const f32x4*)&accs[3][row][c4];
    float inv = 1.f / L;
    f32x4 o;
#pragma unroll
    for (int j = 0; j < 4; ++j)
      o[j] = (s0 * a0[j] + s1 * a1[j] + s2 * a2[j] + s3 * a3[j]) * inv;
    *(f32x4*)(out + (size_t)(b * T_ + qbase + row) * DQ + c4) = o;
  }
}

extern "C" void kernel_launch(void* const* d_in, const int* in_sizes, int n_in,
                              void* d_out, int out_size, void* d_ws, size_t ws_size,
                              hipStream_t stream)
{
  const float* x  = (const float*)d_in[0];
  const float* Wq = (const float*)d_in[1];
  const float* Wk = (const float*)d_in[2];
  const float* Wv = (const float*)d_in[3];
  float* out = (float*)d_out;

  char* ws = (char*)d_ws;
  __bf16* Wf = (__bf16*)(ws);                                   // 384 KiB
  __bf16* Qb = (__bf16*)(ws + 0x80000);                         // 2 MiB
  __bf16* Kb = (__bf16*)(ws + 0x80000 + 0x200000);              // 2 MiB
  __bf16* Vt = (__bf16*)(ws + 0x80000 + 0x400000);              // 2 MiB

  kw_pack<<<96, 256, 0, stream>>>(Wq, Wk, Wv, Wf);
  kproj<<<256, 256, 0, stream>>>(x, Wf, Qb, Kb, Vt);
  kattn<<<512, 256, 0, stream>>>(Qb, Kb, Vt, out);
}

// Round 7
// 51.665 us; speedup vs baseline: 2.6090x; 2.6090x over previous
//
#include <hip/hip_runtime.h>

typedef float f32x4 __attribute__((ext_vector_type(4)));
typedef __bf16 bf16x8 __attribute__((ext_vector_type(8)));
typedef __bf16 bf16x4 __attribute__((ext_vector_type(4)));

#define T_ 2048
#define DE 1024
#define DQ 64
#define SCALE 0.125f

#define GL16(gp, lp)                                                        \
  __builtin_amdgcn_global_load_lds(                                         \
      (const __attribute__((address_space(1))) void*)(gp),                  \
      (__attribute__((address_space(3))) void*)(lp), 16, 0, 0)

#define WAITVM0 asm volatile("s_waitcnt vmcnt(0)" ::: "memory")

// ---------- kernel 0: pack W (3x [1024][64] f32) into fragment-major bf16 Wf.
// Wf[(kc*12 + t)*64 + lane][8]: elem j = W[kc*32+(lane>>4)*8+j][(t&3)*16+(lane&15)],
// matrix = t>>2, kc = k/32.  (validated R5/R6)
__global__ __launch_bounds__(256) void kw_pack(
    const float* __restrict__ Wq, const float* __restrict__ Wk,
    const float* __restrict__ Wv, __bf16* __restrict__ Wf)
{
  int tid = blockIdx.x * 256 + threadIdx.x;   // 0..24575 = f*64 + lane
  int lane = tid & 63, f = tid >> 6;
  int t = f % 12, kc = f / 12;
  const float* W = (t < 4) ? Wq : ((t < 8) ? Wk : Wv);
  int nl = (t & 3) * 16 + (lane & 15);
  int k0 = kc * 32 + (lane >> 4) * 8;
  bf16x8 v;
#pragma unroll
  for (int j = 0; j < 8; ++j) v[j] = (__bf16)W[(size_t)(k0 + j) * 64 + nl];
  *(bf16x8*)(Wf + (size_t)tid * 8) = v;
}

// ---------- kernel 1: QKV projection. Block = 32 m-rows, 4 waves = 2 msub x 2 ngrp.
// BOTH x and W staged per k-step via global_load_lds (all-VMEM fire-and-forget
// stream, no reg-load waits in the loop). Double-buffered 2x32KB LDS,
// WAITVM(0)+s_barrier per step, ds_read fragments (lgkmcnt, compiler-managed).
__global__ __launch_bounds__(256) void kproj(
    const float* __restrict__ x, const __bf16* __restrict__ Wf,
    __bf16* __restrict__ Qb, __bf16* __restrict__ Kb, __bf16* __restrict__ Vt)
{
  __shared__ char lds[2][32768];              // [buf][ A:8KB | B:24KB ]  = 64 KB
  const int tid = threadIdx.x;
  const int lane = tid & 63;
  const int w = tid >> 6;
  const int col = lane & 15, g = lane >> 4;
  const int msub = w & 1;                     // 16-row half
  const int ng = w >> 1;                      // n-tile group: tiles ng*6 .. ng*6+5
  const int mbase = blockIdx.x * 32;

  // --- staging map: 8 x 1KB wave-chunks per thread per k-step (2 A + 6 B).
  // A chunk q = w*2+cc (q<8): rows q*4+(l>>4), 16B slot (l&15), source
  // pre-swizzled by ((row&7)<<4) (same involution applied on reads).
  // B chunk j = w*6+cc-2 (j<24): linear copy of Wf's contiguous 24KB step slab.
  size_t gbase[8];
  int gstride[8], ldst[8];
#pragma unroll
  for (int cc = 0; cc < 2; ++cc) {
    int q = w * 2 + cc;
    int row = q * 4 + (lane >> 4);
    int kbyte = ((lane & 15) * 16) ^ ((row & 7) << 4);
    gbase[cc] = (size_t)(mbase + row) * 4096 + (size_t)kbyte;   // into x (bytes)
    gstride[cc] = 256;                                          // 64 floats/step
    ldst[cc] = q * 1024 + lane * 16;                            // A region [0,8K)
  }
#pragma unroll
  for (int cc = 2; cc < 8; ++cc) {
    int j = w * 6 + cc - 2;
    gbase[cc] = (size_t)j * 1024 + (size_t)lane * 16;           // into Wf (bytes)
    gstride[cc] = 24576;                                        // 24KB/step
    ldst[cc] = 8192 + j * 1024 + lane * 16;                     // B region [8K,32K)
  }

  f32x4 acc[6];
#pragma unroll
  for (int i = 0; i < 6; ++i) acc[i] = (f32x4){0.f, 0.f, 0.f, 0.f};

  const char* xb = (const char*)x;
  const char* wb = (const char*)Wf;

#define STAGE(ks, bi)                                                       \
  {                                                                         \
    char* lb = &lds[bi][0];                                                 \
    _Pragma("unroll")                                                       \
    for (int cc = 0; cc < 2; ++cc)                                          \
      GL16(xb + gbase[cc] + (size_t)(ks) * gstride[cc], lb + ldst[cc]);     \
    _Pragma("unroll")                                                       \
    for (int cc = 2; cc < 8; ++cc)                                          \
      GL16(wb + gbase[cc] + (size_t)(ks) * gstride[cc], lb + ldst[cc]);     \
  }

#define KSTEP(ks, bi)                                                       \
  {                                                                         \
    const char* la = &lds[bi][0];                                           \
    const char* lbB = &lds[bi][8192];                                       \
    const int arow = msub * 16 + col;                                       \
    const char* abase = la + arow * 256;                                    \
    const int sw = (arow & 7) << 4;                                         \
    _Pragma("unroll")                                                       \
    for (int kh = 0; kh < 2; ++kh) {                                        \
      int kb = kh * 128 + g * 32;                                           \
      f32x4 a0 = *(const f32x4*)(abase + (kb ^ sw));                        \
      f32x4 a1 = *(const f32x4*)(abase + ((kb + 16) ^ sw));                 \
      bf16x8 af;                                                            \
      _Pragma("unroll")                                                     \
      for (int j = 0; j < 4; ++j) { af[j] = (__bf16)a0[j]; af[4 + j] = (__bf16)a1[j]; } \
      _Pragma("unroll")                                                     \
      for (int ii = 0; ii < 6; ++ii) {                                      \
        int nt = ng * 6 + ii;                                               \
        bf16x8 bfr = *(const bf16x8*)(lbB + ((kh * 12 + nt) * 64 + lane) * 16); \
        acc[ii] = __builtin_amdgcn_mfma_f32_16x16x32_bf16(af, bfr, acc[ii], 0, 0, 0); \
      }                                                                     \
    }                                                                       \
  }

  STAGE(0, 0);
  for (int ks = 0; ks < 16; ++ks) {
    WAITVM0;                                  // own stage(ks) landed
    __builtin_amdgcn_s_barrier();             // all waves' stage(ks) landed
    __builtin_amdgcn_sched_barrier(0);
    if (ks < 15) STAGE(ks + 1, (ks + 1) & 1); // overwrites buf read at ks-1: safe
    KSTEP(ks, ks & 1);
  }

#undef STAGE
#undef KSTEP

  // epilogue: D layout row = g*4+r (within 16-row m-sub), col = ti*16 + col
  const int b = mbase >> 11;
  const int mrow = mbase + msub * 16 + g * 4;
  const int trow = (mbase & 2047) + msub * 16 + g * 4;
#pragma unroll
  for (int ii = 0; ii < 6; ++ii) {
    int ti = ng * 6 + ii;
    if (ti < 8) {
      __bf16* dst = (ti < 4) ? Qb : Kb;
      int c = (ti & 3) * 16 + col;
#pragma unroll
      for (int r = 0; r < 4; ++r)
        dst[(size_t)(mrow + r) * DQ + c] = (__bf16)acc[ii][r];
    } else {
      int d = (ti - 8) * 16 + col;
      bf16x4 v;
#pragma unroll
      for (int r = 0; r < 4; ++r) v[r] = (__bf16)acc[ii][r];
      *(bf16x4*)(Vt + ((size_t)(b * DQ + d)) * T_ + trow) = v;
    }
  }
}

// ---------- kernel 2: causal flash attention (R3 version, proven ~23us).
// Block = 32 q-rows, 4 waves split KV (KVB=64), LDS combine.
__global__ __launch_bounds__(256) void kattn(
    const __bf16* __restrict__ Qb, const __bf16* __restrict__ Kb,
    const __bf16* __restrict__ Vt, float* __restrict__ out)
{
  __shared__ float accs[4][32][68];
  __shared__ float mls[4][2][32];
  __shared__ __bf16 plds[4][2][16][72];

  const int tid = threadIdx.x;
  const int lane = tid & 63;
  const int w = tid >> 6;
  const int col = lane & 15, g = lane >> 4;
  const int b = blockIdx.x & 7;
  const int jq = 63 - (blockIdx.x >> 3);
  const int qbase = jq * 32;

  bf16x8 qa[2][2];
#pragma unroll
  for (int mt = 0; mt < 2; ++mt) {
    const __bf16* Qp = Qb + (size_t)(b * T_ + qbase + mt * 16 + col) * DQ + g * 8;
    qa[mt][0] = *(const bf16x8*)(Qp);
    qa[mt][1] = *(const bf16x8*)(Qp + 32);
  }

  const __bf16* Kbb = Kb + (size_t)b * T_ * DQ;
  const __bf16* Vbb = Vt + (size_t)b * DQ * T_;

  f32x4 acc[2][4];
#pragma unroll
  for (int mt = 0; mt < 2; ++mt)
#pragma unroll
    for (int dt = 0; dt < 4; ++dt) acc[mt][dt] = (f32x4){0.f,0.f,0.f,0.f};
  float mrun[2][4], lsum[2][4];
#pragma unroll
  for (int mt = 0; mt < 2; ++mt)
#pragma unroll
    for (int r = 0; r < 4; ++r) { mrun[mt][r] = -1e30f; lsum[mt][r] = 0.f; }

  const int nb = (jq >> 1) + 1;
  for (int it = w; it < nb; it += 4) {
    const int nbase = it * 64;

    bf16x8 kf_[4][2];
#pragma unroll
    for (int nt = 0; nt < 4; ++nt) {
      const __bf16* Kp = Kbb + (size_t)(nbase + nt * 16 + col) * DQ + g * 8;
      kf_[nt][0] = *(const bf16x8*)(Kp);
      kf_[nt][1] = *(const bf16x8*)(Kp + 32);
    }

    f32x4 s[2][4];
#pragma unroll
    for (int mt = 0; mt < 2; ++mt)
#pragma unroll
      for (int nt = 0; nt < 4; ++nt) {
        f32x4 t = __builtin_amdgcn_mfma_f32_16x16x32_bf16(qa[mt][0], kf_[nt][0],
                                                          (f32x4){0.f,0.f,0.f,0.f}, 0, 0, 0);
        s[mt][nt] = __builtin_amdgcn_mfma_f32_16x16x32_bf16(qa[mt][1], kf_[nt][1], t, 0, 0, 0);
      }

    bf16x8 vf[4][2];
#pragma unroll
    for (int dt = 0; dt < 4; ++dt) {
      const __bf16* Vp = Vbb + (size_t)(dt * 16 + col) * T_ + nbase + g * 8;
      vf[dt][0] = *(const bf16x8*)(Vp);
      vf[dt][1] = *(const bf16x8*)(Vp + 32);
    }

#pragma unroll
    for (int mt = 0; mt < 2; ++mt)
#pragma unroll
      for (int nt = 0; nt < 4; ++nt)
#pragma unroll
        for (int r = 0; r < 4; ++r) s[mt][nt][r] *= SCALE;
    if (it == nb - 1) {
#pragma unroll
      for (int mt = 0; mt < 2; ++mt)
#pragma unroll
        for (int nt = 0; nt < 4; ++nt)
#pragma unroll
          for (int r = 0; r < 4; ++r)
            if (nbase + nt * 16 + col > qbase + mt * 16 + g * 4 + r) s[mt][nt][r] = -1e30f;
    }

    float mv[2][4];
#pragma unroll
    for (int mt = 0; mt < 2; ++mt)
#pragma unroll
      for (int r = 0; r < 4; ++r)
        mv[mt][r] = fmaxf(fmaxf(s[mt][0][r], s[mt][1][r]), fmaxf(s[mt][2][r], s[mt][3][r]));
#pragma unroll
    for (int sh = 1; sh <= 8; sh <<= 1)
#pragma unroll
      for (int mt = 0; mt < 2; ++mt)
#pragma unroll
        for (int r = 0; r < 4; ++r) mv[mt][r] = fmaxf(mv[mt][r], __shfl_xor(mv[mt][r], sh, 64));

#pragma unroll
    for (int mt = 0; mt < 2; ++mt)
#pragma unroll
      for (int r = 0; r < 4; ++r) {
        float mn = fmaxf(mrun[mt][r], mv[mt][r]);
        float rs = __expf(mrun[mt][r] - mn);
        mrun[mt][r] = mn;
        float ps = 0.f;
#pragma unroll
        for (int nt = 0; nt < 4; ++nt) {
          s[mt][nt][r] = __expf(s[mt][nt][r] - mn);
          ps += s[mt][nt][r];
        }
        lsum[mt][r] = lsum[mt][r] * rs + ps;
#pragma unroll
        for (int dt = 0; dt < 4; ++dt) acc[mt][dt][r] *= rs;
      }

#pragma unroll
    for (int mt = 0; mt < 2; ++mt)
#pragma unroll
      for (int nt = 0; nt < 4; ++nt)
#pragma unroll
        for (int r = 0; r < 4; ++r)
          plds[w][mt][g * 4 + r][nt * 16 + col] = (__bf16)s[mt][nt][r];

    bf16x8 pa[2][2];
#pragma unroll
    for (int mt = 0; mt < 2; ++mt) {
      pa[mt][0] = *(const bf16x8*)&plds[w][mt][col][g * 8];
      pa[mt][1] = *(const bf16x8*)&plds[w][mt][col][32 + g * 8];
    }

#pragma unroll
    for (int mt = 0; mt < 2; ++mt)
#pragma unroll
      for (int dt = 0; dt < 4; ++dt) {
        f32x4 t = __builtin_amdgcn_mfma_f32_16x16x32_bf16(pa[mt][0], vf[dt][0], acc[mt][dt], 0, 0, 0);
        acc[mt][dt] = __builtin_amdgcn_mfma_f32_16x16x32_bf16(pa[mt][1], vf[dt][1], t, 0, 0, 0);
      }
  }

#pragma unroll
  for (int sh = 1; sh <= 8; sh <<= 1)
#pragma unroll
    for (int mt = 0; mt < 2; ++mt)
#pragma unroll
      for (int r = 0; r < 4; ++r) lsum[mt][r] += __shfl_xor(lsum[mt][r], sh, 64);

#pragma unroll
  for (int mt = 0; mt < 2; ++mt)
#pragma unroll
    for (int r = 0; r < 4; ++r) {
      int row = mt * 16 + g * 4 + r;
      accs[w][row][col]      = acc[mt][0][r];
      accs[w][row][col + 16] = acc[mt][1][r];
      accs[w][row][col + 32] = acc[mt][2][r];
      accs[w][row][col + 48] = acc[mt][3][r];
      if (col == 0) { mls[w][0][row] = mrun[mt][r]; mls[w][1][row] = lsum[mt][r]; }
    }
  __syncthreads();

#pragma unroll
  for (int pass = 0; pass < 2; ++pass) {
    int row = pass * 16 + (tid >> 4);
    int c4 = (tid & 15) * 4;
    float m0 = mls[0][0][row], m1 = mls[1][0][row];
    float m2 = mls[2][0][row], m3 = mls[3][0][row];
    float M = fmaxf(fmaxf(m0, m1), fmaxf(m2, m3));
    float s0 = __expf(m0 - M), s1 = __expf(m1 - M);
    float s2 = __expf(m2 - M), s3 = __expf(m3 - M);
    float L = s0 * mls[0][1][row] + s1 * mls[1][1][row]
            + s2 * mls[2][1][row] + s3 * mls[3][1][row];
    f32x4 a0 = *(const f32x4*)&accs[0][row][c4];
    f32x4 a1 = *(const f32x4*)&accs[1][row][c4];
    f32x4 a2 = *(const f32x4*)&accs[2][row][c4];
    f32x4 a3 = *(const f32x4*)&accs[3][row][c4];
    float inv = 1.f / L;
    f32x4 o;
#pragma unroll
    for (int j = 0; j < 4; ++j)
      o[j] = (s0 * a0[j] + s1 * a1[j] + s2 * a2[j] + s3 * a3[j]) * inv;
    *(f32x4*)(out + (size_t)(b * T_ + qbase + row) * DQ + c4) = o;
  }
}

extern "C" void kernel_launch(void* const* d_in, const int* in_sizes, int n_in,
                              void* d_out, int out_size, void* d_ws, size_t ws_size,
                              hipStream_t stream)
{
  const float* x  = (const float*)d_in[0];
  const float* Wq = (const float*)d_in[1];
  const float* Wk = (const float*)d_in[2];
  const float* Wv = (const float*)d_in[3];
  float* out = (float*)d_out;

  char* ws = (char*)d_ws;
  __bf16* Wf = (__bf16*)(ws);                                   // 384 KiB
  __bf16* Qb = (__bf16*)(ws + 0x80000);                         // 2 MiB
  __bf16* Kb = (__bf16*)(ws + 0x80000 + 0x200000);              // 2 MiB
  __bf16* Vt = (__bf16*)(ws + 0x80000 + 0x400000);              // 2 MiB

  kw_pack<<<96, 256, 0, stream>>>(Wq, Wk, Wv, Wf);
  kproj<<<512, 256, 0, stream>>>(x, Wf, Qb, Kb, Vt);
  kattn<<<512, 256, 0, stream>>>(Qb, Kb, Vt, out);
}